// Round 10
// baseline (139.416 us; speedup 1.0000x reference)
//
#include <hip/hip_runtime.h>
#include <math.h>

#define NSRC 2048
#define HID  1024
#define NORD 32
#define FSTR 72   // LDS row stride (bf16) for fourier kernel

typedef __bf16 bf16_t;
typedef bf16_t bf16x8 __attribute__((ext_vector_type(8)));
typedef bf16_t bf16x4 __attribute__((ext_vector_type(4)));
typedef float  f32x4  __attribute__((ext_vector_type(4)));

__device__ __forceinline__ float gelu_f(float x) {
  float u = 0.7978845608028654f * x * (1.0f + 0.044715f * x * x);
  return 0.5f * x * (1.0f + tanhf(u));
}

// async global->LDS, 16 B per lane. LDS dest is wave-uniform base + lane*16
// (we pass the per-lane ptr; lane 0's value IS the wave base since dest is
// linear tid*16). Global src is per-lane (pre-swizzled address).
#define GLL(g, l)                                                            \
  __builtin_amdgcn_global_load_lds(                                          \
      (const __attribute__((address_space(1))) void*)(g),                    \
      (__attribute__((address_space(3))) void*)(l), 16, 0, 0)

// Fused: h1 = gelu(sources @ W1.T + b1) -> bf16; W2/W3 fp32 -> bf16; zero hsum.
__global__ __launch_bounds__(256) void head_kernel(
    const float* __restrict__ sources, const float* __restrict__ W1,
    const float* __restrict__ b1, bf16_t* __restrict__ h1b,
    const float* __restrict__ W2, const float* __restrict__ W3,
    bf16_t* __restrict__ W2b, bf16_t* __restrict__ W3b,
    float* __restrict__ hsum) {
  int idx = blockIdx.x * 256 + threadIdx.x;          // 2M total
  if (blockIdx.x == 0) {
    for (int c = threadIdx.x; c < HID; c += 256) hsum[c] = 0.0f;
  }
  const int HALF = HID * HID / 4;                     // 262144 float4s
  if (idx < 2 * HALF) {
    const float* src = (idx < HALF) ? W2 : W3;
    bf16_t* dst = (idx < HALF) ? W2b : W3b;
    int j = (idx < HALF) ? idx : idx - HALF;
    float4 v = ((const float4*)src)[j];
    bf16x4 o = {(bf16_t)v.x, (bf16_t)v.y, (bf16_t)v.z, (bf16_t)v.w};
    ((bf16x4*)dst)[j] = o;
  }
  int s = idx >> 10;
  int n = idx & (HID - 1);
  float4 src4 = *(const float4*)(sources + 4 * s);
  float4 w    = *(const float4*)(W1 + 4 * n);
  float z = src4.x * w.x + src4.y * w.y + src4.z * w.z + src4.w * w.w + b1[n];
  h1b[idx] = (bf16_t)gelu_f(z);
}

// C = gelu(A @ B^T + bias). A (2048,1024), B (1024,1024), bf16 NT.
// BM=BN=64, BK=64. global_load_lds staging (no reg round-trip, no ds_write):
// per k-step, issue next tile's 4 async loads right AFTER the barrier, then
// compute the current buffer — the next barrier's implicit vmcnt(0) drain
// gives each load a full compute phase in flight. XOR swizzle stays on the
// GLOBAL address (lc = pc ^ (row&7)); LDS dest is linear tid*16B as
// global_load_lds requires. Grid 512 = 2 blocks/CU.
template <bool WRITE_C, bool COLSUM>
__global__ __launch_bounds__(256) void gemm_bf16_mfma(
    const bf16_t* __restrict__ A, const bf16_t* __restrict__ B,
    const float* __restrict__ bias, bf16_t* __restrict__ C,
    float* __restrict__ hsum) {
  const int K = 1024, NDIM = 1024;
  __shared__ bf16_t As[2][64 * 64];   // 8 KB each
  __shared__ bf16_t Bs[2][64 * 64];
  const int tid  = threadIdx.x;
  const int wave = tid >> 6;
  const int lane = tid & 63;
  const int tm = blockIdx.y * 64;
  const int tn = blockIdx.x * 64;
  const int wm = (wave & 1) * 32;
  const int wn = (wave >> 1) * 32;

  // staging: thread t owns 16B chunks {t, t+256} of each 64x64 tile.
  // chunk c -> row c>>3, phys chunk c&7; fetch logical lc = pc ^ (row&7);
  // chunk t+256 is row+32, same row&7 -> same lc.
  const int row0 = tid >> 3;           // 0..31
  const int pc   = tid & 7;
  const int lc   = pc ^ (row0 & 7);
  const bf16_t* gA = A + (size_t)(tm + row0) * K + lc * 8;
  const bf16_t* gB = B + (size_t)(tn + row0) * K + lc * 8;

  const int col15 = lane & 15;
  const int quad  = lane >> 4;
  const int rsw   = col15 & 7;
  f32x4 acc[2][2] = {};

  // prologue: issue k0=0 tile into buf 0 (drained by first barrier)
  GLL(gA,                     &As[0][tid * 8]);
  GLL(gA + (size_t)32 * K,    &As[0][(tid + 256) * 8]);
  GLL(gB,                     &Bs[0][tid * 8]);
  GLL(gB + (size_t)32 * K,    &Bs[0][(tid + 256) * 8]);

#define COMPUTE_TILE(b)                                                        \
  do {                                                                         \
    _Pragma("unroll")                                                          \
    for (int s = 0; s < 2; ++s) {                                              \
      const int pck = (s * 4 + quad) ^ rsw;                                    \
      bf16x8 a0 = *(const bf16x8*)(&As[b][(wm + col15) * 64 + pck * 8]);       \
      bf16x8 a1 = *(const bf16x8*)(&As[b][(wm + 16 + col15) * 64 + pck * 8]);  \
      bf16x8 b0 = *(const bf16x8*)(&Bs[b][(wn + col15) * 64 + pck * 8]);       \
      bf16x8 b1 = *(const bf16x8*)(&Bs[b][(wn + 16 + col15) * 64 + pck * 8]);  \
      acc[0][0] = __builtin_amdgcn_mfma_f32_16x16x32_bf16(a0, b0, acc[0][0], 0, 0, 0); \
      acc[0][1] = __builtin_amdgcn_mfma_f32_16x16x32_bf16(a0, b1, acc[0][1], 0, 0, 0); \
      acc[1][0] = __builtin_amdgcn_mfma_f32_16x16x32_bf16(a1, b0, acc[1][0], 0, 0, 0); \
      acc[1][1] = __builtin_amdgcn_mfma_f32_16x16x32_bf16(a1, b1, acc[1][1], 0, 0, 0); \
    }                                                                          \
  } while (0)

  for (int k0 = 0; k0 < K; k0 += 64) {
    const int buf = (k0 >> 6) & 1;
    // barrier: each wave's own outstanding global_load_lds (into `buf`) are
    // vmcnt-drained before it passes; all waves passed => buf fully staged.
    __syncthreads();
    if (k0 + 64 < K) {   // issue next tile into buf^1; in flight over compute
      GLL(gA + k0 + 64,                  &As[buf ^ 1][tid * 8]);
      GLL(gA + (size_t)32 * K + k0 + 64, &As[buf ^ 1][(tid + 256) * 8]);
      GLL(gB + k0 + 64,                  &Bs[buf ^ 1][tid * 8]);
      GLL(gB + (size_t)32 * K + k0 + 64, &Bs[buf ^ 1][(tid + 256) * 8]);
    }
    COMPUTE_TILE(buf);
  }
#undef COMPUTE_TILE

  const int rq = quad * 4;
#pragma unroll
  for (int j = 0; j < 2; ++j) {
    const int col = tn + wn + j * 16 + col15;
    const float bj = bias[col];
    float cs = 0.0f;
#pragma unroll
    for (int i = 0; i < 2; ++i) {
      const int rbase = tm + wm + i * 16 + rq;
#pragma unroll
      for (int p = 0; p < 4; ++p) {
        float v = gelu_f(acc[i][j][p] + bj);
        if (WRITE_C) C[(size_t)(rbase + p) * NDIM + col] = (bf16_t)v;
        if (COLSUM) cs += v;
      }
    }
    if (COLSUM) {
      cs += __shfl_xor(cs, 16, 64);
      cs += __shfl_xor(cs, 32, 64);
      if (lane < 16) atomicAdd(&hsum[col], cs);
    }
  }
}

// wsum[o] = W4[o,:].hsum + S*b4[o], emitted as bf16 into packed Wbig[64][64]:
//   o=(c,i,j): m = i + 32*(c==1||c==3), k = j + 32*(c==1||c==2)
// block 1024: bsum = (sum_s sources[s].Wb) + S*bb
__global__ __launch_bounds__(256) void gemv_kernel(
    const float* __restrict__ W4, const float* __restrict__ hsum,
    const float* __restrict__ b4, bf16_t* __restrict__ Wbig,
    const float* __restrict__ sources, const float* __restrict__ Wb,
    const float* __restrict__ bb, float* __restrict__ bsum) {
  if (blockIdx.x == 1024) {
    float a = 0.0f;
    float w0 = Wb[0], w1 = Wb[1], w2 = Wb[2], w3 = Wb[3];
    for (int s = threadIdx.x; s < NSRC; s += 256) {
      float4 src = *(const float4*)(sources + 4 * s);
      a += src.x * w0 + src.y * w1 + src.z * w2 + src.w * w3;
    }
#pragma unroll
    for (int off = 32; off; off >>= 1) a += __shfl_down(a, off, 64);
    __shared__ float wred[4];
    if ((threadIdx.x & 63) == 0) wred[threadIdx.x >> 6] = a;
    __syncthreads();
    if (threadIdx.x == 0)
      bsum[0] = wred[0] + wred[1] + wred[2] + wred[3] + (float)NSRC * bb[0];
    return;
  }
  int o = blockIdx.x * 4 + (threadIdx.x >> 6);   // 0..4095
  int lane = threadIdx.x & 63;
  const float* row = W4 + (size_t)o * HID;
  float acc = 0.0f;
#pragma unroll
  for (int t = 0; t < 4; ++t) {
    float4 rv = *(const float4*)(row + t * 256 + lane * 4);
    float4 hv = *(const float4*)(hsum + t * 256 + lane * 4);
    acc = fmaf(rv.x, hv.x, acc);
    acc = fmaf(rv.y, hv.y, acc);
    acc = fmaf(rv.z, hv.z, acc);
    acc = fmaf(rv.w, hv.w, acc);
  }
#pragma unroll
  for (int off = 32; off; off >>= 1) acc += __shfl_down(acc, off, 64);
  if (lane == 0) {
    float val = acc + (float)NSRC * b4[o];
    int c = o >> 10, i5 = (o >> 5) & 31, j5 = o & 31;
    int m = i5 + (((c == 1) || (c == 3)) ? 32 : 0);
    int k = j5 + (((c == 1) || (c == 2)) ? 32 : 0);
    Wbig[m * 64 + k] = (bf16_t)val;
  }
}

// out[n] = bsum + x(n)^T (Wbig z(n)),  x=[cx;sx], z=[cy;sy] (64-dim each).
// Trig via hw v_fract + v_sin/v_cos (input in revolutions: a * r/10) —
// validated rounds 6-9 (absmax unchanged at 128).
__global__ __launch_bounds__(256) void fourier_mfma(
    const float* __restrict__ r, const bf16_t* __restrict__ Wbig,
    const float* __restrict__ bsum, float* __restrict__ out, int N) {
  __shared__ bf16_t Ws[64 * FSTR];
  __shared__ bf16_t Zs[64 * FSTR];   // [pt][k]
  __shared__ bf16_t Xs[64 * FSTR];   // [pt][m]
  const int tid  = threadIdx.x;
  const int wave = tid >> 6;
  const int lane = tid & 63;

  {
    const bf16x8* Wg = (const bf16x8*)Wbig;
    bf16x8 w0 = Wg[2 * tid], w1 = Wg[2 * tid + 1];
    int wrow = tid >> 2;
    int wcol = (tid & 3) * 16;
    *(bf16x8*)(Ws + wrow * FSTR + wcol) = w0;
    *(bf16x8*)(Ws + wrow * FSTR + wcol + 8) = w1;
  }

  {
    const int p = tid >> 2, q = tid & 3;
    int n = blockIdx.x * 64 + p;
    if (n >= N) n = N - 1;
    // angle = 2*pi * a * (r/10)  ->  revolutions = a * (r*0.1);
    // v_sin/v_cos take revolutions after v_fract range-reduction.
    float rx = r[2 * n] * 0.1f, ry = r[2 * n + 1] * 0.1f;
    float a = (float)(q + 1);
    float f1x = __builtin_amdgcn_fractf(a * rx);
    float f4x = __builtin_amdgcn_fractf(4.0f * rx);
    float f1y = __builtin_amdgcn_fractf(a * ry);
    float f4y = __builtin_amdgcn_fractf(4.0f * ry);
    float s1x = __builtin_amdgcn_sinf(f1x), c1x = __builtin_amdgcn_cosf(f1x);
    float s4x = __builtin_amdgcn_sinf(f4x), c4x = __builtin_amdgcn_cosf(f4x);
    float s1y = __builtin_amdgcn_sinf(f1y), c1y = __builtin_amdgcn_cosf(f1y);
    float s4y = __builtin_amdgcn_sinf(f4y), c4y = __builtin_amdgcn_cosf(f4y);
    float cxv = c1x, sxv = s1x, cyv = c1y, syv = s1y;
#pragma unroll
    for (int t = 0; t < 8; ++t) {
      int j = q + 4 * t;
      Zs[p * FSTR + j]      = (bf16_t)cyv;
      Zs[p * FSTR + 32 + j] = (bf16_t)syv;
      Xs[p * FSTR + j]      = (bf16_t)cxv;
      Xs[p * FSTR + 32 + j] = (bf16_t)sxv;
      float tc = cxv * c4x - sxv * s4x; sxv = sxv * c4x + cxv * s4x; cxv = tc;
      tc = cyv * c4y - syv * s4y; syv = syv * c4y + cyv * s4y; cyv = tc;
    }
  }
  __syncthreads();

  const int col15 = lane & 15;
  const int quad  = lane >> 4;
  const int q8    = quad * 8;
  f32x4 G[4] = {};
#pragma unroll
  for (int kc = 0; kc < 2; ++kc) {
    bf16x8 bz = *(const bf16x8*)(Zs + (wave * 16 + col15) * FSTR + kc * 32 + q8);
#pragma unroll
    for (int mt = 0; mt < 4; ++mt) {
      bf16x8 af = *(const bf16x8*)(Ws + (mt * 16 + col15) * FSTR + kc * 32 + q8);
      G[mt] = __builtin_amdgcn_mfma_f32_16x16x32_bf16(af, bz, G[mt], 0, 0, 0);
    }
  }

  const int pt = wave * 16 + col15;
  float s = 0.0f;
#pragma unroll
  for (int mt = 0; mt < 4; ++mt) {
    bf16x4 xv = *(const bf16x4*)(Xs + pt * FSTR + mt * 16 + quad * 4);
    s += (float)xv[0] * G[mt][0] + (float)xv[1] * G[mt][1] +
         (float)xv[2] * G[mt][2] + (float)xv[3] * G[mt][3];
  }
  s += __shfl_xor(s, 16, 64);
  s += __shfl_xor(s, 32, 64);
  if (lane < 16) {
    int n2 = blockIdx.x * 64 + pt;
    if (n2 >= N) n2 = N - 1;
    out[n2] = s + bsum[0];
  }
}

extern "C" void kernel_launch(void* const* d_in, const int* in_sizes, int n_in,
                              void* d_out, int out_size, void* d_ws, size_t ws_size,
                              hipStream_t stream) {
  const float* sources = (const float*)d_in[0];
  const float* r   = (const float*)d_in[1];
  const float* W1  = (const float*)d_in[2];
  const float* b1  = (const float*)d_in[3];
  const float* W2  = (const float*)d_in[4];
  const float* b2  = (const float*)d_in[5];
  const float* W3  = (const float*)d_in[6];
  const float* b3  = (const float*)d_in[7];
  const float* W4  = (const float*)d_in[8];
  const float* b4  = (const float*)d_in[9];
  const float* Wb  = (const float*)d_in[10];
  const float* bb  = (const float*)d_in[11];
  float* out = (float*)d_out;

  char* ws = (char*)d_ws;
  bf16_t* h1b  = (bf16_t*)(ws);                         // 4 MB
  bf16_t* h2b  = (bf16_t*)(ws + (4 << 20));             // 4 MB
  bf16_t* W2b  = (bf16_t*)(ws + (8 << 20));             // 2 MB
  bf16_t* W3b  = (bf16_t*)(ws + (10 << 20));            // 2 MB
  float*  hsum = (float*)(ws + (12 << 20));             // 4 KB
  bf16_t* Wbig = (bf16_t*)(ws + (12 << 20) + 4096);     // 8 KB
  float*  bsum = (float*)(ws + (12 << 20) + 16384);     // 4 B

  int N = out_size;                       // 100000 points

  head_kernel<<<NSRC * HID / 256, 256, 0, stream>>>(
      sources, W1, b1, h1b, W2, W3, W2b, W3b, hsum);
  gemm_bf16_mfma<true, false><<<dim3(HID / 64, NSRC / 64), 256, 0, stream>>>(
      h1b, W2b, b2, h2b, nullptr);
  gemm_bf16_mfma<false, true><<<dim3(HID / 64, NSRC / 64), 256, 0, stream>>>(
      h2b, W3b, b3, nullptr, hsum);
  gemv_kernel<<<1025, 256, 0, stream>>>(W4, hsum, b4, Wbig, sources, Wb, bb, bsum);
  fourier_mfma<<<(N + 63) / 64, 256, 0, stream>>>(r, Wbig, bsum, out, N);
}

// Round 11
// 126.541 us; speedup vs baseline: 1.1017x; 1.1017x over previous
//
#include <hip/hip_runtime.h>
#include <math.h>

#define NSRC 2048
#define HID  1024
#define NORD 32
#define FSTR 72   // LDS row stride (bf16) for fourier kernel

typedef __bf16 bf16_t;
typedef bf16_t bf16x8 __attribute__((ext_vector_type(8)));
typedef bf16_t bf16x4 __attribute__((ext_vector_type(4)));
typedef float  f32x4  __attribute__((ext_vector_type(4)));

__device__ __forceinline__ float gelu_f(float x) {
  float u = 0.7978845608028654f * x * (1.0f + 0.044715f * x * x);
  return 0.5f * x * (1.0f + tanhf(u));
}

// Fused: h1 = gelu(sources @ W1.T + b1) -> bf16; W2/W3 fp32 -> bf16; zero hsum.
__global__ __launch_bounds__(256) void head_kernel(
    const float* __restrict__ sources, const float* __restrict__ W1,
    const float* __restrict__ b1, bf16_t* __restrict__ h1b,
    const float* __restrict__ W2, const float* __restrict__ W3,
    bf16_t* __restrict__ W2b, bf16_t* __restrict__ W3b,
    float* __restrict__ hsum) {
  int idx = blockIdx.x * 256 + threadIdx.x;          // 2M total
  if (blockIdx.x == 0) {
    for (int c = threadIdx.x; c < HID; c += 256) hsum[c] = 0.0f;
  }
  const int HALF = HID * HID / 4;                     // 262144 float4s
  if (idx < 2 * HALF) {
    const float* src = (idx < HALF) ? W2 : W3;
    bf16_t* dst = (idx < HALF) ? W2b : W3b;
    int j = (idx < HALF) ? idx : idx - HALF;
    float4 v = ((const float4*)src)[j];
    bf16x4 o = {(bf16_t)v.x, (bf16_t)v.y, (bf16_t)v.z, (bf16_t)v.w};
    ((bf16x4*)dst)[j] = o;
  }
  int s = idx >> 10;
  int n = idx & (HID - 1);
  float4 src4 = *(const float4*)(sources + 4 * s);
  float4 w    = *(const float4*)(W1 + 4 * n);
  float z = src4.x * w.x + src4.y * w.y + src4.z * w.z + src4.w * w.w + b1[n];
  h1b[idx] = (bf16_t)gelu_f(z);
}

// C = gelu(A @ B^T + bias). A (2048,1024), B (1024,1024), bf16 NT.
// BM=BN=64, BK=64. TWO-DEEP register prefetch + LDS double-buffer: regs hold
// tiles i and i+1; at iter i we ds_write tile i and issue loads for tile i+2,
// which drain at ds_write of iter i+2 — ~2 k-steps of latency cover (vs 1 in
// the round-9 scheme). Loop unrolled x2 with named per-phase registers so
// all indexing is static. One barrier per k-step; barrier at iter i still
// separates iter i-1's compute from iter i's writes (structure unchanged).
// XOR swizzle (phys chunk = logical ^ (row&7)). Grid 512 = 2 blocks/CU.
template <bool WRITE_C, bool COLSUM>
__global__ __launch_bounds__(256) void gemm_bf16_mfma(
    const bf16_t* __restrict__ A, const bf16_t* __restrict__ B,
    const float* __restrict__ bias, bf16_t* __restrict__ C,
    float* __restrict__ hsum) {
  const int K = 1024, NDIM = 1024;
  __shared__ bf16_t As[2][64 * 64];   // 8 KB each
  __shared__ bf16_t Bs[2][64 * 64];
  const int tid  = threadIdx.x;
  const int wave = tid >> 6;
  const int lane = tid & 63;
  const int tm = blockIdx.y * 64;
  const int tn = blockIdx.x * 64;
  const int wm = (wave & 1) * 32;
  const int wn = (wave >> 1) * 32;

  // staging: thread t owns 16B chunks {t, t+256} of each 64x64 tile.
  // chunk c -> row c>>3, phys chunk c&7; fetch logical lc = pc ^ (row&7);
  // chunk t+256 is row+32, same row&7 -> same lc.
  const int row0 = tid >> 3;           // 0..31
  const int pc   = tid & 7;
  const int lc   = pc ^ (row0 & 7);
  const bf16_t* gA = A + (size_t)(tm + row0) * K + lc * 8;
  const bf16_t* gB = B + (size_t)(tn + row0) * K + lc * 8;

  const int col15 = lane & 15;
  const int quad  = lane >> 4;
  const int rsw   = col15 & 7;
  f32x4 acc[2][2] = {};

  // prologue: tiles 0 (p-regs) and 1 (q-regs)
  bf16x8 pa0 = *(const bf16x8*)(gA);
  bf16x8 pa1 = *(const bf16x8*)(gA + (size_t)32 * K);
  bf16x8 pb0 = *(const bf16x8*)(gB);
  bf16x8 pb1 = *(const bf16x8*)(gB + (size_t)32 * K);
  bf16x8 qa0 = *(const bf16x8*)(gA + 64);
  bf16x8 qa1 = *(const bf16x8*)(gA + (size_t)32 * K + 64);
  bf16x8 qb0 = *(const bf16x8*)(gB + 64);
  bf16x8 qb1 = *(const bf16x8*)(gB + (size_t)32 * K + 64);

#define COMPUTE_TILE(b)                                                        \
  do {                                                                         \
    _Pragma("unroll")                                                          \
    for (int s = 0; s < 2; ++s) {                                              \
      const int pck = (s * 4 + quad) ^ rsw;                                    \
      bf16x8 a0 = *(const bf16x8*)(&As[b][(wm + col15) * 64 + pck * 8]);       \
      bf16x8 a1 = *(const bf16x8*)(&As[b][(wm + 16 + col15) * 64 + pck * 8]);  \
      bf16x8 b0 = *(const bf16x8*)(&Bs[b][(wn + col15) * 64 + pck * 8]);       \
      bf16x8 b1 = *(const bf16x8*)(&Bs[b][(wn + 16 + col15) * 64 + pck * 8]);  \
      acc[0][0] = __builtin_amdgcn_mfma_f32_16x16x32_bf16(a0, b0, acc[0][0], 0, 0, 0); \
      acc[0][1] = __builtin_amdgcn_mfma_f32_16x16x32_bf16(a0, b1, acc[0][1], 0, 0, 0); \
      acc[1][0] = __builtin_amdgcn_mfma_f32_16x16x32_bf16(a1, b0, acc[1][0], 0, 0, 0); \
      acc[1][1] = __builtin_amdgcn_mfma_f32_16x16x32_bf16(a1, b1, acc[1][1], 0, 0, 0); \
    }                                                                          \
  } while (0)

#pragma unroll 1
  for (int kk = 0; kk < 8; ++kk) {
    const int k0 = kk * 128;
    // even phase: buf 0, tile 2kk (p-regs); load tile 2kk+2 into p-regs
    __syncthreads();
    *(bf16x8*)(&As[0][tid * 8])         = pa0;
    *(bf16x8*)(&As[0][(tid + 256) * 8]) = pa1;
    *(bf16x8*)(&Bs[0][tid * 8])         = pb0;
    *(bf16x8*)(&Bs[0][(tid + 256) * 8]) = pb1;
    if (k0 + 128 < K) {
      pa0 = *(const bf16x8*)(gA + k0 + 128);
      pa1 = *(const bf16x8*)(gA + (size_t)32 * K + k0 + 128);
      pb0 = *(const bf16x8*)(gB + k0 + 128);
      pb1 = *(const bf16x8*)(gB + (size_t)32 * K + k0 + 128);
    }
    if (kk > 0) COMPUTE_TILE(1);   // tile 2kk-1 (written last odd phase)
    // odd phase: buf 1, tile 2kk+1 (q-regs); load tile 2kk+3 into q-regs
    __syncthreads();
    *(bf16x8*)(&As[1][tid * 8])         = qa0;
    *(bf16x8*)(&As[1][(tid + 256) * 8]) = qa1;
    *(bf16x8*)(&Bs[1][tid * 8])         = qb0;
    *(bf16x8*)(&Bs[1][(tid + 256) * 8]) = qb1;
    if (k0 + 192 < K) {
      qa0 = *(const bf16x8*)(gA + k0 + 192);
      qa1 = *(const bf16x8*)(gA + (size_t)32 * K + k0 + 192);
      qb0 = *(const bf16x8*)(gB + k0 + 192);
      qb1 = *(const bf16x8*)(gB + (size_t)32 * K + k0 + 192);
    }
    COMPUTE_TILE(0);               // tile 2kk (written this even phase)
  }
  __syncthreads();     // last odd write visible across waves
  COMPUTE_TILE(1);     // tile 15
#undef COMPUTE_TILE

  const int rq = quad * 4;
#pragma unroll
  for (int j = 0; j < 2; ++j) {
    const int col = tn + wn + j * 16 + col15;
    const float bj = bias[col];
    float cs = 0.0f;
#pragma unroll
    for (int i = 0; i < 2; ++i) {
      const int rbase = tm + wm + i * 16 + rq;
#pragma unroll
      for (int p = 0; p < 4; ++p) {
        float v = gelu_f(acc[i][j][p] + bj);
        if (WRITE_C) C[(size_t)(rbase + p) * NDIM + col] = (bf16_t)v;
        if (COLSUM) cs += v;
      }
    }
    if (COLSUM) {
      cs += __shfl_xor(cs, 16, 64);
      cs += __shfl_xor(cs, 32, 64);
      if (lane < 16) atomicAdd(&hsum[col], cs);
    }
  }
}

// wsum[o] = W4[o,:].hsum + S*b4[o], emitted as bf16 into packed Wbig[64][64]:
//   o=(c,i,j): m = i + 32*(c==1||c==3), k = j + 32*(c==1||c==2)
// block 1024: bsum = (sum_s sources[s].Wb) + S*bb
__global__ __launch_bounds__(256) void gemv_kernel(
    const float* __restrict__ W4, const float* __restrict__ hsum,
    const float* __restrict__ b4, bf16_t* __restrict__ Wbig,
    const float* __restrict__ sources, const float* __restrict__ Wb,
    const float* __restrict__ bb, float* __restrict__ bsum) {
  if (blockIdx.x == 1024) {
    float a = 0.0f;
    float w0 = Wb[0], w1 = Wb[1], w2 = Wb[2], w3 = Wb[3];
    for (int s = threadIdx.x; s < NSRC; s += 256) {
      float4 src = *(const float4*)(sources + 4 * s);
      a += src.x * w0 + src.y * w1 + src.z * w2 + src.w * w3;
    }
#pragma unroll
    for (int off = 32; off; off >>= 1) a += __shfl_down(a, off, 64);
    __shared__ float wred[4];
    if ((threadIdx.x & 63) == 0) wred[threadIdx.x >> 6] = a;
    __syncthreads();
    if (threadIdx.x == 0)
      bsum[0] = wred[0] + wred[1] + wred[2] + wred[3] + (float)NSRC * bb[0];
    return;
  }
  int o = blockIdx.x * 4 + (threadIdx.x >> 6);   // 0..4095
  int lane = threadIdx.x & 63;
  const float* row = W4 + (size_t)o * HID;
  float acc = 0.0f;
#pragma unroll
  for (int t = 0; t < 4; ++t) {
    float4 rv = *(const float4*)(row + t * 256 + lane * 4);
    float4 hv = *(const float4*)(hsum + t * 256 + lane * 4);
    acc = fmaf(rv.x, hv.x, acc);
    acc = fmaf(rv.y, hv.y, acc);
    acc = fmaf(rv.z, hv.z, acc);
    acc = fmaf(rv.w, hv.w, acc);
  }
#pragma unroll
  for (int off = 32; off; off >>= 1) acc += __shfl_down(acc, off, 64);
  if (lane == 0) {
    float val = acc + (float)NSRC * b4[o];
    int c = o >> 10, i5 = (o >> 5) & 31, j5 = o & 31;
    int m = i5 + (((c == 1) || (c == 3)) ? 32 : 0);
    int k = j5 + (((c == 1) || (c == 2)) ? 32 : 0);
    Wbig[m * 64 + k] = (bf16_t)val;
  }
}

// out[n] = bsum + x(n)^T (Wbig z(n)),  x=[cx;sx], z=[cy;sy] (64-dim each).
// Trig via hw v_fract + v_sin/v_cos (input in revolutions: a * r/10) —
// validated rounds 6-10 (absmax unchanged at 128).
__global__ __launch_bounds__(256) void fourier_mfma(
    const float* __restrict__ r, const bf16_t* __restrict__ Wbig,
    const float* __restrict__ bsum, float* __restrict__ out, int N) {
  __shared__ bf16_t Ws[64 * FSTR];
  __shared__ bf16_t Zs[64 * FSTR];   // [pt][k]
  __shared__ bf16_t Xs[64 * FSTR];   // [pt][m]
  const int tid  = threadIdx.x;
  const int wave = tid >> 6;
  const int lane = tid & 63;

  {
    const bf16x8* Wg = (const bf16x8*)Wbig;
    bf16x8 w0 = Wg[2 * tid], w1 = Wg[2 * tid + 1];
    int wrow = tid >> 2;
    int wcol = (tid & 3) * 16;
    *(bf16x8*)(Ws + wrow * FSTR + wcol) = w0;
    *(bf16x8*)(Ws + wrow * FSTR + wcol + 8) = w1;
  }

  {
    const int p = tid >> 2, q = tid & 3;
    int n = blockIdx.x * 64 + p;
    if (n >= N) n = N - 1;
    // angle = 2*pi * a * (r/10)  ->  revolutions = a * (r*0.1);
    // v_sin/v_cos take revolutions after v_fract range-reduction.
    float rx = r[2 * n] * 0.1f, ry = r[2 * n + 1] * 0.1f;
    float a = (float)(q + 1);
    float f1x = __builtin_amdgcn_fractf(a * rx);
    float f4x = __builtin_amdgcn_fractf(4.0f * rx);
    float f1y = __builtin_amdgcn_fractf(a * ry);
    float f4y = __builtin_amdgcn_fractf(4.0f * ry);
    float s1x = __builtin_amdgcn_sinf(f1x), c1x = __builtin_amdgcn_cosf(f1x);
    float s4x = __builtin_amdgcn_sinf(f4x), c4x = __builtin_amdgcn_cosf(f4x);
    float s1y = __builtin_amdgcn_sinf(f1y), c1y = __builtin_amdgcn_cosf(f1y);
    float s4y = __builtin_amdgcn_sinf(f4y), c4y = __builtin_amdgcn_cosf(f4y);
    float cxv = c1x, sxv = s1x, cyv = c1y, syv = s1y;
#pragma unroll
    for (int t = 0; t < 8; ++t) {
      int j = q + 4 * t;
      Zs[p * FSTR + j]      = (bf16_t)cyv;
      Zs[p * FSTR + 32 + j] = (bf16_t)syv;
      Xs[p * FSTR + j]      = (bf16_t)cxv;
      Xs[p * FSTR + 32 + j] = (bf16_t)sxv;
      float tc = cxv * c4x - sxv * s4x; sxv = sxv * c4x + cxv * s4x; cxv = tc;
      tc = cyv * c4y - syv * s4y; syv = syv * c4y + cyv * s4y; cyv = tc;
    }
  }
  __syncthreads();

  const int col15 = lane & 15;
  const int quad  = lane >> 4;
  const int q8    = quad * 8;
  f32x4 G[4] = {};
#pragma unroll
  for (int kc = 0; kc < 2; ++kc) {
    bf16x8 bz = *(const bf16x8*)(Zs + (wave * 16 + col15) * FSTR + kc * 32 + q8);
#pragma unroll
    for (int mt = 0; mt < 4; ++mt) {
      bf16x8 af = *(const bf16x8*)(Ws + (mt * 16 + col15) * FSTR + kc * 32 + q8);
      G[mt] = __builtin_amdgcn_mfma_f32_16x16x32_bf16(af, bz, G[mt], 0, 0, 0);
    }
  }

  const int pt = wave * 16 + col15;
  float s = 0.0f;
#pragma unroll
  for (int mt = 0; mt < 4; ++mt) {
    bf16x4 xv = *(const bf16x4*)(Xs + pt * FSTR + mt * 16 + quad * 4);
    s += (float)xv[0] * G[mt][0] + (float)xv[1] * G[mt][1] +
         (float)xv[2] * G[mt][2] + (float)xv[3] * G[mt][3];
  }
  s += __shfl_xor(s, 16, 64);
  s += __shfl_xor(s, 32, 64);
  if (lane < 16) {
    int n2 = blockIdx.x * 64 + pt;
    if (n2 >= N) n2 = N - 1;
    out[n2] = s + bsum[0];
  }
}

extern "C" void kernel_launch(void* const* d_in, const int* in_sizes, int n_in,
                              void* d_out, int out_size, void* d_ws, size_t ws_size,
                              hipStream_t stream) {
  const float* sources = (const float*)d_in[0];
  const float* r   = (const float*)d_in[1];
  const float* W1  = (const float*)d_in[2];
  const float* b1  = (const float*)d_in[3];
  const float* W2  = (const float*)d_in[4];
  const float* b2  = (const float*)d_in[5];
  const float* W3  = (const float*)d_in[6];
  const float* b3  = (const float*)d_in[7];
  const float* W4  = (const float*)d_in[8];
  const float* b4  = (const float*)d_in[9];
  const float* Wb  = (const float*)d_in[10];
  const float* bb  = (const float*)d_in[11];
  float* out = (float*)d_out;

  char* ws = (char*)d_ws;
  bf16_t* h1b  = (bf16_t*)(ws);                         // 4 MB
  bf16_t* h2b  = (bf16_t*)(ws + (4 << 20));             // 4 MB
  bf16_t* W2b  = (bf16_t*)(ws + (8 << 20));             // 2 MB
  bf16_t* W3b  = (bf16_t*)(ws + (10 << 20));            // 2 MB
  float*  hsum = (float*)(ws + (12 << 20));             // 4 KB
  bf16_t* Wbig = (bf16_t*)(ws + (12 << 20) + 4096);     // 8 KB
  float*  bsum = (float*)(ws + (12 << 20) + 16384);     // 4 B

  int N = out_size;                       // 100000 points

  head_kernel<<<NSRC * HID / 256, 256, 0, stream>>>(
      sources, W1, b1, h1b, W2, W3, W2b, W3b, hsum);
  gemm_bf16_mfma<true, false><<<dim3(HID / 64, NSRC / 64), 256, 0, stream>>>(
      h1b, W2b, b2, h2b, nullptr);
  gemm_bf16_mfma<false, true><<<dim3(HID / 64, NSRC / 64), 256, 0, stream>>>(
      h2b, W3b, b3, nullptr, hsum);
  gemv_kernel<<<1025, 256, 0, stream>>>(W4, hsum, b4, Wbig, sources, Wb, bb, bsum);
  fourier_mfma<<<(N + 63) / 64, 256, 0, stream>>>(r, Wbig, bsum, out, N);
}